// Round 1
// baseline (504.387 us; speedup 1.0000x reference)
//
#include <hip/hip_runtime.h>
#include <hip/hip_bf16.h>
#include <stdint.h>

// ProjectiveAttention: out = softmax(h @ W @ h^T) @ h
// B=8, S=2048, D=800, all fp32 in/out.
// Strategy: bf16 hi/lo split (3-product MFMA emulation) for hW and scores,
// plain bf16 MFMA for PV. Scores materialized per batch-chunk in ws;
// softmax writes bf16 attn in place (pitch 4096 bf16 within fp32 rows).

#define BB 8
#define SS 2048
#define DD 800
#define NPAD 896          // zero-padded row count for 128-wide N tiles (7*128=896)
#define M1 (BB*SS)        // 16384

typedef unsigned short u16;
typedef __attribute__((ext_vector_type(8))) short bf16x8;
typedef __attribute__((ext_vector_type(4))) float f32x4;

__device__ __forceinline__ u16 f2bf(float x) {
    uint32_t u = __float_as_uint(x);
    uint32_t r = (u + 0x7fffu + ((u >> 16) & 1u)) >> 16;  // RTN-even
    return (u16)r;
}
__device__ __forceinline__ float bf2f(u16 h) {
    return __uint_as_float(((uint32_t)h) << 16);
}

__device__ __forceinline__ void gload16(const void* g, void* l) {
    __builtin_amdgcn_global_load_lds((__attribute__((address_space(1))) void*)g,
                                     (__attribute__((address_space(3))) void*)l,
                                     16, 0, 0);
}

// ---------------- prep kernels ----------------

// h (fp32) -> h_hi, h_lo (bf16 split), vectorized float4
__global__ __launch_bounds__(256) void hsplit_kernel(const float4* __restrict__ x,
                                                     u16* __restrict__ hi,
                                                     u16* __restrict__ lo, int n4) {
    int i = blockIdx.x * 256 + threadIdx.x;
    if (i >= n4) return;
    float4 v = x[i];
    u16 h0 = f2bf(v.x), h1 = f2bf(v.y), h2 = f2bf(v.z), h3 = f2bf(v.w);
    ushort4 hv = {h0, h1, h2, h3};
    ushort4 lv = {f2bf(v.x - bf2f(h0)), f2bf(v.y - bf2f(h1)),
                  f2bf(v.z - bf2f(h2)), f2bf(v.w - bf2f(h3))};
    *(ushort4*)(hi + (size_t)i * 4) = hv;
    *(ushort4*)(lo + (size_t)i * 4) = lv;
}

// W (fp32 [D][D]) -> Wt_hi/Wt_lo (bf16 [NPAD][D], transposed, pad rows zeroed)
__global__ __launch_bounds__(256) void wsplit_kernel(const float* __restrict__ W,
                                                     u16* __restrict__ hi,
                                                     u16* __restrict__ lo) {
    int idx = blockIdx.x * 256 + threadIdx.x;
    if (idx >= NPAD * DD) return;
    int e = idx / DD, d = idx - e * DD;
    float v = (e < DD) ? W[(size_t)d * DD + e] : 0.f;
    u16 h = f2bf(v);
    hi[idx] = h;
    lo[idx] = f2bf(v - bf2f(h));
}

// h_hi (bf16 [B][S][D]) -> hT (bf16 [B][NPAD][S], transposed per batch, pad zeroed)
__global__ void transpose_kernel(const u16* __restrict__ h_hi, u16* __restrict__ hT) {
    __shared__ u16 tile[32][33];
    int b = blockIdx.z;
    int t0 = blockIdx.x * 32, d0 = blockIdx.y * 32;
    int lx = threadIdx.x, ly = threadIdx.y;
    for (int i = ly; i < 32; i += 8) {
        int t = t0 + i, d = d0 + lx;
        tile[i][lx] = (d < DD) ? h_hi[(size_t)b * SS * DD + (size_t)t * DD + d] : (u16)0;
    }
    __syncthreads();
    for (int i = ly; i < 32; i += 8) {
        int d = d0 + i, t = t0 + lx;
        hT[(size_t)b * NPAD * SS + (size_t)d * SS + t] = tile[lx][i];
    }
}

// ---------------- softmax (one block per row, in-place fp32 -> bf16 attn) --------

__global__ __launch_bounds__(256) void softmax_kernel(float* __restrict__ scores) {
    const long row = blockIdx.x;
    float* p = scores + row * (long)SS;
    const int tid = threadIdx.x;
    const int lane = tid & 63, wid = tid >> 6;
    __shared__ float red[8];

    float v[8];
    float mx = -3.4e38f;
#pragma unroll
    for (int j = 0; j < 8; ++j) { v[j] = p[tid + 256 * j]; mx = fmaxf(mx, v[j]); }
#pragma unroll
    for (int o = 32; o; o >>= 1) mx = fmaxf(mx, __shfl_xor(mx, o, 64));
    if (lane == 0) red[wid] = mx;
    __syncthreads();
    mx = fmaxf(fmaxf(red[0], red[1]), fmaxf(red[2], red[3]));

    float sum = 0.f;
#pragma unroll
    for (int j = 0; j < 8; ++j) { v[j] = __expf(v[j] - mx); sum += v[j]; }
#pragma unroll
    for (int o = 32; o; o >>= 1) sum += __shfl_xor(sum, o, 64);
    if (lane == 0) red[4 + wid] = sum;
    __syncthreads();
    const float inv = 1.f / (red[4] + red[5] + red[6] + red[7]);

    // all reads of p[] completed before the barriers above -> safe in-place bf16 write
    u16* attn = (u16*)p;
#pragma unroll
    for (int j = 0; j < 8; ++j) attn[tid + 256 * j] = f2bf(v[j] * inv);
}

// ---------------- GEMM: C[m][n] = sum_k A[m][k] * B[n][k]  (both K-contiguous) ----
// SPLIT3: A,B given as hi/lo pairs, accumulate hi*hi + hi*lo + lo*hi
// SPLIT_OUT: write C as bf16 hi/lo split instead of fp32
// NGUARD: guard column store at Nlim (operand rows must be padded/zeroed to tile)

template <int SPLIT3, int SPLIT_OUT, int NGUARD>
__global__ __launch_bounds__(256) void gemm_kernel(
    const u16* __restrict__ Ahi, const u16* __restrict__ Alo, long sA, int lda,
    const u16* __restrict__ Bhi, const u16* __restrict__ Blo, long sB, int ldb,
    float* __restrict__ C, u16* __restrict__ Chi, u16* __restrict__ Clo,
    long sC, int ldc, int Nlim, int ksteps) {
    constexpr int PARTS = SPLIT3 ? 2 : 1;
    __shared__ __align__(16) u16 lsA[PARTS * 4096];  // [part][128 rows][32 k] bf16
    __shared__ __align__(16) u16 lsB[PARTS * 4096];

    const int tid = threadIdx.x;
    const int lane = tid & 63, wid = tid >> 6;
    const int zb = blockIdx.z;
    const int m0 = blockIdx.x * 128, n0 = blockIdx.y * 128;

    const u16* Ah = Ahi + (long)zb * sA;
    const u16* Bh = Bhi + (long)zb * sB;
    const u16* Al = SPLIT3 ? (Alo + (long)zb * sA) : nullptr;
    const u16* Bl = SPLIT3 ? (Blo + (long)zb * sB) : nullptr;

    const int srow = tid >> 2;          // staging row within 64-row chunk
    const int scol = (tid & 3) * 8;     // staging k-offset (bf16 elems)
    const int wm = wid >> 1, wn = wid & 1;
    const int arow = wm * 64 + (lane & 15);
    const int brow = wn * 64 + (lane & 15);
    const int kb = (lane >> 4) * 8;

    f32x4 acc[4][4];
#pragma unroll
    for (int i = 0; i < 4; ++i)
#pragma unroll
        for (int j = 0; j < 4; ++j) acc[i][j] = (f32x4){0.f, 0.f, 0.f, 0.f};

    char* lA = (char*)lsA + wid * 1024;  // wave-uniform LDS staging base
    char* lB = (char*)lsB + wid * 1024;

    for (int ks = 0; ks < ksteps; ++ks) {
        const int k0 = ks * 32;
        __syncthreads();  // previous iter's ds_reads complete before overwrite
        {
            const u16* g = Ah + (long)(m0 + srow) * lda + (k0 + scol);
            gload16(g, lA);
            gload16(g + (long)64 * lda, lA + 4096);
            const u16* gb = Bh + (long)(n0 + srow) * ldb + (k0 + scol);
            gload16(gb, lB);
            gload16(gb + (long)64 * ldb, lB + 4096);
            if (SPLIT3) {
                const u16* g2 = Al + (long)(m0 + srow) * lda + (k0 + scol);
                gload16(g2, lA + 8192);
                gload16(g2 + (long)64 * lda, lA + 12288);
                const u16* gb2 = Bl + (long)(n0 + srow) * ldb + (k0 + scol);
                gload16(gb2, lB + 8192);
                gload16(gb2 + (long)64 * ldb, lB + 12288);
            }
        }
        __syncthreads();  // vmcnt(0) drained by compiler before barrier

        bf16x8 ah[4], bh[4], al[4], bl[4];
#pragma unroll
        for (int f = 0; f < 4; ++f) {
            ah[f] = *(const bf16x8*)&lsA[(arow + f * 16) * 32 + kb];
            bh[f] = *(const bf16x8*)&lsB[(brow + f * 16) * 32 + kb];
            if (SPLIT3) {
                al[f] = *(const bf16x8*)&lsA[4096 + (arow + f * 16) * 32 + kb];
                bl[f] = *(const bf16x8*)&lsB[4096 + (brow + f * 16) * 32 + kb];
            }
        }
#pragma unroll
        for (int i = 0; i < 4; ++i)
#pragma unroll
            for (int j = 0; j < 4; ++j) {
                acc[i][j] = __builtin_amdgcn_mfma_f32_16x16x32_bf16(ah[i], bh[j], acc[i][j], 0, 0, 0);
                if (SPLIT3) {
                    acc[i][j] = __builtin_amdgcn_mfma_f32_16x16x32_bf16(ah[i], bl[j], acc[i][j], 0, 0, 0);
                    acc[i][j] = __builtin_amdgcn_mfma_f32_16x16x32_bf16(al[i], bh[j], acc[i][j], 0, 0, 0);
                }
            }
    }

    // epilogue: C/D layout col=lane&15, row=(lane>>4)*4+reg  [m89-verified]
    const int crow = m0 + wm * 64 + (lane >> 4) * 4;
    const int ccol = n0 + wn * 64 + (lane & 15);
#pragma unroll
    for (int i = 0; i < 4; ++i) {
#pragma unroll
        for (int j = 0; j < 4; ++j) {
            const int nn = ccol + j * 16;
            if (NGUARD && nn >= Nlim) continue;
#pragma unroll
            for (int r = 0; r < 4; ++r) {
                const int mm = crow + i * 16 + r;
                const long off = (long)zb * sC + (long)mm * ldc + nn;
                if (SPLIT_OUT) {
                    float v = acc[i][j][r];
                    u16 hh = f2bf(v);
                    Chi[off] = hh;
                    Clo[off] = f2bf(v - bf2f(hh));
                } else {
                    C[off] = acc[i][j][r];
                }
            }
        }
    }
}

// ---------------- host ----------------

extern "C" void kernel_launch(void* const* d_in, const int* in_sizes, int n_in,
                              void* d_out, int out_size, void* d_ws, size_t ws_size,
                              hipStream_t stream) {
    const float* h = (const float*)d_in[0];
    const float* W = (const float*)d_in[1];
    float* out = (float*)d_out;

    char* ws = (char*)d_ws;
    size_t off = 0;
    auto alloc = [&](size_t bytes) -> void* {
        void* p = ws + off;
        off += (bytes + 255) & ~(size_t)255;
        return p;
    };
    const size_t MD = (size_t)BB * SS * DD;
    u16* h_hi  = (u16*)alloc(MD * 2);
    u16* h_lo  = (u16*)alloc(MD * 2);
    u16* hW_hi = (u16*)alloc(MD * 2);
    u16* hW_lo = (u16*)alloc(MD * 2);
    u16* hT    = (u16*)alloc((size_t)BB * NPAD * SS * 2);
    u16* Wt_hi = (u16*)alloc((size_t)NPAD * DD * 2);
    u16* Wt_lo = (u16*)alloc((size_t)NPAD * DD * 2);

    size_t remain = (ws_size > off) ? (ws_size - off) : 0;
    const size_t batch_bytes = (size_t)SS * SS * 4;
    int nb = (int)(remain / batch_bytes);
    if (nb < 1) nb = 1;
    if (nb > BB) nb = BB;
    float* scores = (float*)alloc((size_t)nb * batch_bytes);

    // prep: splits + transpose
    hsplit_kernel<<<dim3((unsigned)(MD / 4 / 256)), dim3(256), 0, stream>>>(
        (const float4*)h, h_hi, h_lo, (int)(MD / 4));
    wsplit_kernel<<<dim3((NPAD * DD + 255) / 256), dim3(256), 0, stream>>>(W, Wt_hi, Wt_lo);
    transpose_kernel<<<dim3(SS / 32, NPAD / 32, BB), dim3(32, 8), 0, stream>>>(h_hi, hT);

    // GEMM1: hW = h @ W   (M=16384, N=800 -> 7 tiles, K=800 -> 25 steps), split-out
    gemm_kernel<1, 1, 1><<<dim3(M1 / 128, 7, 1), dim3(256), 0, stream>>>(
        h_hi, h_lo, 0L, DD,
        Wt_hi, Wt_lo, 0L, DD,
        (float*)nullptr, hW_hi, hW_lo, 0L, DD, DD, DD / 32);

    for (int b0 = 0; b0 < BB; b0 += nb) {
        int nbc = (BB - b0 < nb) ? (BB - b0) : nb;
        // GEMM2: scores = hW @ h^T  (per-batch M=N=2048, K=800)
        gemm_kernel<1, 0, 0><<<dim3(SS / 128, SS / 128, nbc), dim3(256), 0, stream>>>(
            hW_hi + (size_t)b0 * SS * DD, hW_lo + (size_t)b0 * SS * DD, (long)SS * DD, DD,
            h_hi + (size_t)b0 * SS * DD, h_lo + (size_t)b0 * SS * DD, (long)SS * DD, DD,
            scores, (u16*)nullptr, (u16*)nullptr, (long)SS * SS, SS, SS, DD / 32);
        // softmax rows, writes bf16 attn in place (pitch 4096 bf16 per row)
        softmax_kernel<<<dim3(nbc * SS), dim3(256), 0, stream>>>(scores);
        // PV: out = attn @ h   (A = attn bf16 pitch 4096, B = hT, M=2048,N=800,K=2048)
        gemm_kernel<0, 0, 1><<<dim3(SS / 128, 7, nbc), dim3(256), 0, stream>>>(
            (const u16*)scores, (const u16*)nullptr, (long)SS * SS * 2, SS * 2,
            hT + (size_t)b0 * NPAD * SS, (const u16*)nullptr, (long)NPAD * SS, SS,
            out + (size_t)b0 * SS * DD, (u16*)nullptr, (u16*)nullptr,
            (long)SS * DD, DD, DD, SS / 32);
    }
}